// Round 4
// baseline (458.182 us; speedup 1.0000x reference)
//
#include <hip/hip_runtime.h>
#include <hip/hip_bf16.h>

typedef unsigned short u16;
typedef unsigned int u32;
typedef __attribute__((ext_vector_type(8))) short bf16x8;   // 8 bf16 = 4 VGPRs
typedef __attribute__((ext_vector_type(4))) float f32x4;
typedef __attribute__((ext_vector_type(2))) unsigned int u32x2;

#define NBATCH 4
#define DDIM   128
#define NHEAD  8
#define PTOT   12544
#define CWID   112     // patch grid width
#define NTOK   49      // tokens per 7x7 window
#define PSTR   68      // p_lds row stride (u16 elems) -> lid stride 2 banks, conflict-free
#define SCALE  0.08838834764831845f

// Single-buffered LDS layout (u16 units):
//   ts  [49][128]  @ 0       (T^T, swizzled; rows >=49 never written — reads land in us, masked)
//   us  [128][64]  @ 6272    (U, swizzled)
//   pl  [49][68]   @ 14464   (P^T, wave-private rows)
//   pcf bf16[1352] @ 17796   (pos bias, bf16)
//   cs  f32[512]   @ 19148
// total 20172 u16 = 40344 B -> LDS allows 4 blocks/CU.
// Register structure (round-3 post-mortem): xfrag[4][4] (64 arch VGPRs) forced a
// ~192-total spill-free floor -> 2 waves/SIMD. This version swaps stage-A tiling:
// wave w owns ITS i-tile (xfrag[4], 16 VGPRs) and loops over all 8 d'/dd tiles.
// Same MFMA count; Gt/Wc read 4x more from L2 (~19 TB/s agg, well under 34.5).
#define OFF_US  6272
#define OFF_PL  14464
#define OFF_PCF 17796
#define OFF_CS  19148
#define LDS_TOT 20172

__device__ __forceinline__ float bf2f(u16 u) {
    union { u32 i; float f; } x; x.i = ((u32)u) << 16; return x.f;
}
__device__ __forceinline__ u16 f2bf(float f) {
    union { float f; u32 u; } v; v.f = f;
    return (u16)((v.u + 0x7fffu + ((v.u >> 16) & 1u)) >> 16);
}
__device__ __forceinline__ u32 pk2(float a, float b) {
    union { __hip_bfloat162 h; u32 u; } c;
    float2 t; t.x = a; t.y = b;
    c.h = __float22bfloat162_rn(t);
    return c.u;
}
__device__ __forceinline__ int swz128(int row, int col) {
    return row * 128 + ((((col >> 3) ^ (row & 15)) & 15) << 3) + (col & 7);
}

// ws layout: u16 Gt (8 x 128x128, row-major d' rows, pre-scaled) | u16 Wc (8 x 128x128) | fp32 block
// fp32 block at u16 offset 262144: bcv[1024] | r[1024] (scaled) | M[1024] (scaled) | s[8] (scaled)
#define WS_WC   131072
#define WS_F32  262144

// ---- prepass (128 blocks = 16 outputs x 8 row-slices) ----
// b<8 -> Wc_h = Wo_h*Wv_h + bcv; b>=8 -> Gt_h = scaled (Wk^T Wq)^T + r/M/s
__global__ void __launch_bounds__(256) prep(
    const float* __restrict__ Wq, const float* __restrict__ Wk,
    const float* __restrict__ Wv, const float* __restrict__ Wo,
    const float* __restrict__ bq, const float* __restrict__ bk,
    const float* __restrict__ bv, u16* __restrict__ ws)
{
    __shared__ u16 lm[18432];           // A-slice 16x128 @0, B 128x128 @2048
    const int tid = threadIdx.x;
    const int bb  = blockIdx.x;
    const int b   = bb >> 3;            // 0..15 (which output matrix)
    const int sub = bb & 7;             // 16-row slice of the output rows
    const bool isG = (b >= 8);
    const int h = b & 7;
    const int r0 = sub * 16;
    float* fb = (float*)(ws + WS_F32);

    if (!isG) {
        for (int idx = tid; idx < 2048; idx += 256) {
            const int lr = idx >> 7, dh = idx & 127;
            lm[swz128(lr, dh)] = f2bf(Wo[(r0 + lr) * 1024 + h * 128 + dh]);
        }
        for (int idx = tid; idx < 16384; idx += 256) {
            const int dh = idx >> 7, d = idx & 127;
            lm[2048 + swz128(d, dh)] = f2bf(Wv[(h * 128 + dh) * 128 + d]);
        }
        if (sub == 0 && tid < 128) {
            float s = 0.f;
            for (int dh = 0; dh < 128; ++dh)
                s += Wo[tid * 1024 + h * 128 + dh] * bv[h * 128 + dh];
            fb[h * 128 + tid] = s;                 // bcv (unscaled)
        }
    } else {
        for (int idx = tid; idx < 2048; idx += 256) {
            const int dh = idx >> 4, lr = idx & 15;
            lm[swz128(lr, dh)] = f2bf(Wk[(h * 128 + dh) * 128 + r0 + lr]);
        }
        for (int idx = tid; idx < 16384; idx += 256) {
            const int dh = idx >> 7, dp = idx & 127;
            lm[2048 + swz128(dp, dh)] = f2bf(Wq[(h * 128 + dh) * 128 + dp]);
        }
        if (sub == 0 && tid < 128) {
            float r = 0.f, m = 0.f;
            for (int dh = 0; dh < 128; ++dh) {
                r += bk[h * 128 + dh] * Wq[(h * 128 + dh) * 128 + tid];
                m += Wk[(h * 128 + dh) * 128 + tid] * bq[h * 128 + dh];
            }
            fb[1024 + h * 128 + tid] = r * SCALE;  // r_h scaled
            fb[2048 + h * 128 + tid] = m * SCALE;  // M_h scaled
        }
        if (sub == 0 && tid == 0) {
            float s = 0.f;
            for (int dh = 0; dh < 128; ++dh) s += bk[h * 128 + dh] * bq[h * 128 + dh];
            fb[3072 + h] = s * SCALE;              // s_h scaled
        }
    }
    __syncthreads();

    const int w = tid >> 6, lane = tid & 63, quad = lane >> 4, lid = lane & 15;
    const f32x4 z4 = {0.f, 0.f, 0.f, 0.f};
    u16* dst = ws + (isG ? 0 : WS_WC) + h * 16384;
    const float gs = isG ? SCALE : 1.0f;
    bf16x8 A[4];
    #pragma unroll
    for (int kt = 0; kt < 4; ++kt)
        A[kt] = *(const bf16x8*)(lm + swz128(lid, kt * 32 + quad * 8));
    #pragma unroll
    for (int ntl = 0; ntl < 2; ++ntl) {
        const int nt = 2 * w + ntl;
        f32x4 acc = z4;
        #pragma unroll
        for (int kt = 0; kt < 4; ++kt) {
            bf16x8 B = *(const bf16x8*)(lm + 2048 + swz128(nt * 16 + lid, kt * 32 + quad * 8));
            acc = __builtin_amdgcn_mfma_f32_16x16x32_bf16(A[kt], B, acc, 0, 0, 0);
        }
        #pragma unroll
        for (int r = 0; r < 4; ++r) {
            const int row = r0 + quad * 4 + r, col = nt * 16 + lid;
            if (isG) dst[col * 128 + row] = f2bf(acc[r] * gs);   // Gt[d'][d] row-major
            else     dst[row * 128 + col] = f2bf(acc[r]);        // Wc[dd][d] row-major
        }
    }
}

// 256 threads = 4 waves; wave w owns token group i/j in [16w,16w+16).
__global__ void __launch_bounds__(256, 3)
winattn(const float* __restrict__ xg, const u16* __restrict__ ws,
        const float* __restrict__ bo, const float* __restrict__ posf,
        float* __restrict__ out)
{
    __shared__ __align__(16) u16 sm[LDS_TOT];
    u16* xw    = sm;                      // staging overlay on ts (49*128 = 6272, exact fit)
    u16* pl    = sm + OFF_PL;             // P^T [j][i], wave-private rows
    u16* pcf16 = sm + OFF_PCF;            // pos bias, bf16
    float* cs  = (float*)(sm + OFF_CS);   // c_i per head

    const int tid  = threadIdx.x;
    const int w    = tid >> 6;
    const int lane = tid & 63;
    const int quad = lane >> 4;
    const int lid  = lane & 15;
    const int bx   = blockIdx.x;
    const int n    = bx >> 8;
    const int win  = bx & 255;
    const int pbase = (win >> 4) * 7 * CWID + (win & 15) * 7;

    const bf16x8 zf = {0,0,0,0,0,0,0,0};
    const f32x4  z4 = {0.f,0.f,0.f,0.f};

    const u16* Gt  = ws;
    const u16* Wcw = ws + WS_WC;
    const float* fb  = (const float*)(ws + WS_F32);
    const float* bcv = fb;
    const float* rP  = fb + 1024;
    const float* MP  = fb + 2048;
    const float* sP  = fb + 3072;

    // ---- stage pos table (bf16) + x window ----
    for (int i = tid; i < 169 * NHEAD; i += 256) pcf16[i] = f2bf(posf[i]);
    const float* xn = xg + n * DDIM * PTOT;
    for (int idx = tid; idx < DDIM * NTOK; idx += 256) {
        int d = idx / NTOK;
        int t = idx - d * NTOK;
        int a = t / 7, b = t - a * 7;
        xw[swz128(t, d)] = f2bf(xn[d * PTOT + pbase + a * CWID + b]);
    }
    __syncthreads();

    // ---- hoist ONLY this wave's i-tile of X (16 VGPRs). It serves as:
    //      stage-A T^T B-operand, stage-A U A-operand, stage-B B-operand (j==i tile),
    //      and the c_i dot operand. ----
    const int j = 16 * w + lid;           // this lane's token (query and key role)
    bf16x8 xfrag[4];
    #pragma unroll
    for (int kt = 0; kt < 4; ++kt)
        xfrag[kt] = (j < NTOK)
            ? *(const bf16x8*)(xw + swz128(j, kt * 32 + quad * 8)) : zf;

    // ---- c_i tables (scaled): cs[h][i] = x_i . M_h + s_h — own i-tile, all heads ----
    for (int hh = 0; hh < NHEAD; ++hh) {
        const float sh = sP[hh];
        float c = 0.f;
        #pragma unroll
        for (int kt = 0; kt < 4; ++kt)
            #pragma unroll
            for (int jj = 0; jj < 8; ++jj)
                c += bf2f((u16)xfrag[kt][jj]) * MP[hh * 128 + kt * 32 + quad * 8 + jj];
        c += __shfl_xor(c, 16);
        c += __shfl_xor(c, 32);
        if (quad == 0) cs[hh * 64 + 16 * w + lid] = c + sh;
    }
    __syncthreads();   // xw dead (ts overlays it); cs visible

    f32x4 outacc[8];
    #pragma unroll
    for (int nt = 0; nt < 8; ++nt) outacc[nt] = z4;

    const int jc = j < NTOK ? j : NTOK - 1;
    const int aj = jc / 7, bj = jc - aj * 7;   // head-invariant

    u16* tsb = sm;               // T^T stored as ts[i<49][d'] swizzled
    u16* usb = sm + OFF_US;      // U stored as us[dd][i] swizzled

    for (int h = 0; h < NHEAD; ++h) {
        // ======== stage A: T^T = G_h x X^T (+r) — wave w owns i-tile w, loops 8 d'-tiles ====
        {
            const int iT = 16 * w + lid;            // output column (token i), fixed
            #pragma unroll
            for (int mt = 0; mt < 8; ++mt) {        // d'-tiles
                bf16x8 A[4];
                #pragma unroll
                for (int kt = 0; kt < 4; ++kt)
                    A[kt] = *(const bf16x8*)(Gt + h * 16384 + (mt * 16 + lid) * 128 + kt * 32 + quad * 8);
                f32x4 acc = z4;
                #pragma unroll
                for (int kt = 0; kt < 4; ++kt)
                    acc = __builtin_amdgcn_mfma_f32_16x16x32_bf16(A[kt], xfrag[kt], acc, 0, 0, 0);
                const int dpb = mt * 16 + quad * 4; // d' base for this lane's 4 outputs
                if (iT < NTOK) {
                    const f32x4 rb = *(const f32x4*)(rP + h * 128 + dpb);
                    u32x2 pkv;
                    pkv.x = pk2(acc[0] + rb[0], acc[1] + rb[1]);
                    pkv.y = pk2(acc[2] + rb[2], acc[3] + rb[3]);
                    *(u32x2*)(tsb + iT * 128 + ((((dpb >> 3) ^ (iT & 15)) & 15) << 3) + (dpb & 7)) = pkv;
                }
            }
        }
        // ======== stage A: U = X x Wc_h^T (+bcv) — wave w owns i-tile w, loops 8 dd-tiles ====
        {
            const int ib = 16 * w + quad * 4;       // output row base (token i), fixed
            #pragma unroll
            for (int nt = 0; nt < 8; ++nt) {        // dd-tiles
                bf16x8 B[4];
                #pragma unroll
                for (int kt = 0; kt < 4; ++kt)
                    B[kt] = *(const bf16x8*)(Wcw + h * 16384 + (nt * 16 + lid) * 128 + kt * 32 + quad * 8);
                f32x4 acc = z4;
                #pragma unroll
                for (int kt = 0; kt < 4; ++kt)
                    acc = __builtin_amdgcn_mfma_f32_16x16x32_bf16(xfrag[kt], B[kt], acc, 0, 0, 0);
                const int dd = nt * 16 + lid;
                const float bb = bcv[h * 128 + dd];
                u32x2 pkv;
                pkv.x = pk2(acc[0] + bb, acc[1] + bb);
                pkv.y = pk2(acc[2] + bb, acc[3] + bb);
                *(u32x2*)(usb + dd * 64 + ((((ib >> 3) ^ (dd & 7)) & 7) << 3) + (ib & 7)) = pkv;
            }
        }
        __syncthreads();   // A done; B/C may read

        // ======== stage B: S = T x X_j^T (+cs+pos), softmax, P write ========
        // A-row reads for i in [49,64) land in the us region: finite bf16, masked below.
        f32x4 S[4];
        #pragma unroll
        for (int mt = 0; mt < 4; ++mt) {
            S[mt] = z4;
            #pragma unroll
            for (int kt = 0; kt < 4; ++kt) {
                bf16x8 Abf = *(const bf16x8*)(tsb + (mt * 16 + lid) * 128 + ((((kt * 4 + quad) ^ lid) & 15) << 3));
                S[mt] = __builtin_amdgcn_mfma_f32_16x16x32_bf16(Abf, xfrag[kt], S[mt], 0, 0, 0);
            }
        }

        float sv[4][4];
        float mx = -3.0e38f;
        #pragma unroll
        for (int mt = 0; mt < 4; ++mt)
            #pragma unroll
            for (int r = 0; r < 4; ++r) {
                const int ii = mt * 16 + quad * 4 + r;
                float vvv;
                if (ii < NTOK) {
                    const int ai = ii / 7, bi = ii - ai * 7;
                    const int rel = (ai - aj + 6) + 13 * (bi - bj + 6);
                    vvv = S[mt][r] + cs[h * 64 + ii] + bf2f(pcf16[rel * NHEAD + h]);
                } else {
                    vvv = -3.0e38f;
                }
                sv[mt][r] = vvv;
                mx = fmaxf(mx, vvv);
            }
        mx = fmaxf(mx, __shfl_xor(mx, 16));
        mx = fmaxf(mx, __shfl_xor(mx, 32));
        float ssum = 0.f;
        #pragma unroll
        for (int mt = 0; mt < 4; ++mt)
            #pragma unroll
            for (int r = 0; r < 4; ++r) {
                const float e = __expf(sv[mt][r] - mx);
                sv[mt][r] = e;
                ssum += e;
            }
        ssum += __shfl_xor(ssum, 16);
        ssum += __shfl_xor(ssum, 32);
        const float inv = 1.0f / ssum;
        if (j < NTOK) {
            #pragma unroll
            for (int mt = 0; mt < 4; ++mt) {
                u32x2 pkv;
                pkv.x = pk2(sv[mt][0] * inv, sv[mt][1] * inv);
                pkv.y = pk2(sv[mt][2] * inv, sv[mt][3] * inv);
                *(u32x2*)(pl + j * PSTR + mt * 16 + quad * 4) = pkv;
            }
        }
        __threadfence_block();   // P rows wave-private: drain + no-reorder suffices

        // ======== stage C: outacc += P^T x U ========
        #pragma unroll
        for (int kt = 0; kt < 2; ++kt) {
            union { bf16x8 v; u32 u[4]; } Af;
            #pragma unroll
            for (int q2 = 0; q2 < 4; ++q2)
                Af.u[q2] = *(const u32*)(pl + jc * PSTR + kt * 32 + quad * 8 + 2 * q2);
            #pragma unroll
            for (int nt = 0; nt < 8; ++nt) {
                const int dd = nt * 16 + lid;
                bf16x8 Bu = *(const bf16x8*)(usb + dd * 64 + ((((kt * 4 + quad) ^ (dd & 7)) & 7) << 3));
                outacc[nt] = __builtin_amdgcn_mfma_f32_16x16x32_bf16(Af.v, Bu, outacc[nt], 0, 0, 0);
            }
        }
        if (h < NHEAD - 1) __syncthreads();   // single buffer: next head rewrites ts/us
    }

    // ======== epilogue: out[n][dd][p(j)] = acc + bo[dd]  (fp32 output) ========
    float* outp = out + n * DDIM * PTOT;
    #pragma unroll
    for (int nt = 0; nt < 8; ++nt) {
        const int dd = nt * 16 + lid;
        const float bov = bo[dd];
        #pragma unroll
        for (int r = 0; r < 4; ++r) {
            const int jj = 16 * w + quad * 4 + r;
            if (jj < NTOK) {
                const int a = jj / 7, b = jj - a * 7;
                outp[dd * PTOT + pbase + a * CWID + b] = outacc[nt][r] + bov;
            }
        }
    }
}

extern "C" void kernel_launch(void* const* d_in, const int* in_sizes, int n_in,
                              void* d_out, int out_size, void* d_ws, size_t ws_size,
                              hipStream_t stream) {
    (void)in_sizes; (void)n_in; (void)ws_size; (void)out_size;
    prep<<<128, 256, 0, stream>>>((const float*)d_in[1], (const float*)d_in[3],
                                  (const float*)d_in[5], (const float*)d_in[7],
                                  (const float*)d_in[2], (const float*)d_in[4],
                                  (const float*)d_in[6], (u16*)d_ws);
    winattn<<<NBATCH * 256, 256, 0, stream>>>(
        (const float*)d_in[0], (const u16*)d_ws,
        (const float*)d_in[8], (const float*)d_in[9], (float*)d_out);
}

// Round 5
// 322.630 us; speedup vs baseline: 1.4201x; 1.4201x over previous
//
#include <hip/hip_runtime.h>
#include <hip/hip_bf16.h>

typedef unsigned short u16;
typedef unsigned int u32;
typedef __attribute__((ext_vector_type(8))) short bf16x8;   // 8 bf16 = 4 VGPRs
typedef __attribute__((ext_vector_type(4))) float f32x4;
typedef __attribute__((ext_vector_type(2))) unsigned int u32x2;

#define NBATCH 4
#define DDIM   128
#define NHEAD  8
#define PTOT   12544
#define CWID   112     // patch grid width
#define NTOK   49      // tokens per 7x7 window
#define PSTR   68      // p_lds row stride (u16 elems)
#define SCALE  0.08838834764831845f

// LDS layout (u16 units) — X persistent, single ts/us buffer, lean registers:
//   ts  [49][128]  @ 0       (T^T swizzled; stray reads rows>=49 land in us: finite bf16)
//   us  [128][64]  @ 6272    (U swizzled)
//   xw  [49][128]  @ 14464   (x window, swz128, PERSISTENT; stray reads land in pl: bf16)
//   pl  [49][68]   @ 20736   (P^T, wave-private rows)
//   pcf bf16[1352] @ 24068   (pos bias, all 8 heads)
//   cs  f32[512]   @ 25420
// total 26444 u16 = 52888 B -> 3 blocks/CU (LDS). Register demand ~140 total
// (arch+AGPR unified) -> (256,3) budget 170 should hold without spill.
#define OFF_US  6272
#define OFF_XW  14464
#define OFF_PL  20736
#define OFF_PCF 24068
#define OFF_CS  25420
#define LDS_TOT 26444

__device__ __forceinline__ float bf2f(u16 u) {
    union { u32 i; float f; } x; x.i = ((u32)u) << 16; return x.f;
}
__device__ __forceinline__ u16 f2bf(float f) {
    union { float f; u32 u; } v; v.f = f;
    return (u16)((v.u + 0x7fffu + ((v.u >> 16) & 1u)) >> 16);
}
__device__ __forceinline__ u32 pk2(float a, float b) {
    union { __hip_bfloat162 h; u32 u; } c;
    float2 t; t.x = a; t.y = b;
    c.h = __float22bfloat162_rn(t);
    return c.u;
}
__device__ __forceinline__ int swz128(int row, int col) {
    return row * 128 + ((((col >> 3) ^ (row & 15)) & 15) << 3) + (col & 7);
}

// ws layout: u16 Gt (8 x 128x128, pre-scaled) | u16 Wc (8 x 128x128) | fp32 block
// fp32 block at u16 offset 262144: bcv[1024] | r[1024] | M[1024] | s[8] (r/M/s scaled)
// partial-out buffer (split mode) at byte offset 1 MiB: [N][D][P] fp32 = 25.7 MB
#define WS_WC   131072
#define WS_F32  262144
#define WS_PART_BYTE (1u << 20)
#define OUT_BYTES (NBATCH * DDIM * PTOT * 4)

// ---- prepass (128 blocks = 16 outputs x 8 row-slices) ----
__global__ void __launch_bounds__(256) prep(
    const float* __restrict__ Wq, const float* __restrict__ Wk,
    const float* __restrict__ Wv, const float* __restrict__ Wo,
    const float* __restrict__ bq, const float* __restrict__ bk,
    const float* __restrict__ bv, u16* __restrict__ ws)
{
    __shared__ u16 lm[18432];           // A-slice 16x128 @0, B 128x128 @2048
    const int tid = threadIdx.x;
    const int bb  = blockIdx.x;
    const int b   = bb >> 3;
    const int sub = bb & 7;
    const bool isG = (b >= 8);
    const int h = b & 7;
    const int r0 = sub * 16;
    float* fb = (float*)(ws + WS_F32);

    if (!isG) {
        for (int idx = tid; idx < 2048; idx += 256) {
            const int lr = idx >> 7, dh = idx & 127;
            lm[swz128(lr, dh)] = f2bf(Wo[(r0 + lr) * 1024 + h * 128 + dh]);
        }
        for (int idx = tid; idx < 16384; idx += 256) {
            const int dh = idx >> 7, d = idx & 127;
            lm[2048 + swz128(d, dh)] = f2bf(Wv[(h * 128 + dh) * 128 + d]);
        }
        if (sub == 0 && tid < 128) {
            float s = 0.f;
            for (int dh = 0; dh < 128; ++dh)
                s += Wo[tid * 1024 + h * 128 + dh] * bv[h * 128 + dh];
            fb[h * 128 + tid] = s;                 // bcv
        }
    } else {
        for (int idx = tid; idx < 2048; idx += 256) {
            const int dh = idx >> 4, lr = idx & 15;
            lm[swz128(lr, dh)] = f2bf(Wk[(h * 128 + dh) * 128 + r0 + lr]);
        }
        for (int idx = tid; idx < 16384; idx += 256) {
            const int dh = idx >> 7, dp = idx & 127;
            lm[2048 + swz128(dp, dh)] = f2bf(Wq[(h * 128 + dh) * 128 + dp]);
        }
        if (sub == 0 && tid < 128) {
            float r = 0.f, m = 0.f;
            for (int dh = 0; dh < 128; ++dh) {
                r += bk[h * 128 + dh] * Wq[(h * 128 + dh) * 128 + tid];
                m += Wk[(h * 128 + dh) * 128 + tid] * bq[h * 128 + dh];
            }
            fb[1024 + h * 128 + tid] = r * SCALE;
            fb[2048 + h * 128 + tid] = m * SCALE;
        }
        if (sub == 0 && tid == 0) {
            float s = 0.f;
            for (int dh = 0; dh < 128; ++dh) s += bk[h * 128 + dh] * bq[h * 128 + dh];
            fb[3072 + h] = s * SCALE;
        }
    }
    __syncthreads();

    const int w = tid >> 6, lane = tid & 63, quad = lane >> 4, lid = lane & 15;
    const f32x4 z4 = {0.f, 0.f, 0.f, 0.f};
    u16* dst = ws + (isG ? 0 : WS_WC) + h * 16384;
    const float gs = isG ? SCALE : 1.0f;
    bf16x8 A[4];
    #pragma unroll
    for (int kt = 0; kt < 4; ++kt)
        A[kt] = *(const bf16x8*)(lm + swz128(lid, kt * 32 + quad * 8));
    #pragma unroll
    for (int ntl = 0; ntl < 2; ++ntl) {
        const int nt = 2 * w + ntl;
        f32x4 acc = z4;
        #pragma unroll
        for (int kt = 0; kt < 4; ++kt) {
            bf16x8 B = *(const bf16x8*)(lm + 2048 + swz128(nt * 16 + lid, kt * 32 + quad * 8));
            acc = __builtin_amdgcn_mfma_f32_16x16x32_bf16(A[kt], B, acc, 0, 0, 0);
        }
        #pragma unroll
        for (int r = 0; r < 4; ++r) {
            const int row = r0 + quad * 4 + r, col = nt * 16 + lid;
            if (isG) dst[col * 128 + row] = f2bf(acc[r] * gs);
            else     dst[row * 128 + col] = f2bf(acc[r]);
        }
    }
}

// 256 threads = 4 waves; wave w owns query group j in [16w,16w+16).
// hsplit=1: grid 2048, block = (n, win, head-half); hp=1 writes partials to part.
__global__ void __launch_bounds__(256, 3)
winattn(const float* __restrict__ xg, const u16* __restrict__ ws,
        const float* __restrict__ bo, const float* __restrict__ posf,
        float* __restrict__ out, float* __restrict__ part, int hsplit)
{
    __shared__ __align__(16) u16 sm[LDS_TOT];
    u16* tsb   = sm;
    u16* usb   = sm + OFF_US;
    u16* xw    = sm + OFF_XW;             // persistent
    u16* pl    = sm + OFF_PL;
    u16* pcf16 = sm + OFF_PCF;
    float* cs  = (float*)(sm + OFF_CS);

    const int tid  = threadIdx.x;
    const int w    = tid >> 6;
    const int lane = tid & 63;
    const int quad = lane >> 4;
    const int lid  = lane & 15;
    const int bx   = blockIdx.x;
    int n, win, hp;
    if (hsplit) { n = bx >> 9; int rem = bx & 511; win = rem >> 1; hp = rem & 1; }
    else        { n = bx >> 8; win = bx & 255; hp = 0; }
    const int hbase = hp * 4;
    const int NH    = hsplit ? 4 : 8;
    const int pbase = (win >> 4) * 7 * CWID + (win & 15) * 7;

    const bf16x8 zf = {0,0,0,0,0,0,0,0};
    const f32x4  z4 = {0.f,0.f,0.f,0.f};

    const u16* Gt  = ws;
    const u16* Wcw = ws + WS_WC;
    const float* fb  = (const float*)(ws + WS_F32);
    const float* bcv = fb;
    const float* rP  = fb + 1024;
    const float* MP  = fb + 2048;
    const float* sP  = fb + 3072;

    // ---- stage pos table (bf16, all heads) + x window (persistent) ----
    for (int i = tid; i < 169 * NHEAD; i += 256) pcf16[i] = f2bf(posf[i]);
    const float* xn = xg + n * DDIM * PTOT;
    for (int idx = tid; idx < DDIM * NTOK; idx += 256) {
        int d = idx / NTOK;
        int t = idx - d * NTOK;
        int a = t / 7, b = t - a * 7;
        xw[swz128(t, d)] = f2bf(xn[d * PTOT + pbase + a * CWID + b]);
    }
    __syncthreads();

    // ---- own j-tile fragments (16 VGPRs): stage-B B-operand ----
    const int j = 16 * w + lid;
    bf16x8 xown[4];
    #pragma unroll
    for (int kt = 0; kt < 4; ++kt)
        xown[kt] = (j < NTOK)
            ? *(const bf16x8*)(xw + swz128(j, kt * 32 + quad * 8)) : zf;

    // ---- c_i tables (scaled) for this block's heads; X read from LDS ----
    for (int hh = hbase + w; hh < hbase + NH; hh += 4) {
        const float sh = sP[hh];
        #pragma unroll
        for (int mt = 0; mt < 4; ++mt) {
            float c = 0.f;
            #pragma unroll
            for (int kt = 0; kt < 4; ++kt) {
                bf16x8 xa = *(const bf16x8*)(xw + swz128(mt * 16 + lid, kt * 32 + quad * 8));
                #pragma unroll
                for (int jj = 0; jj < 8; ++jj)
                    c += bf2f((u16)xa[jj]) * MP[hh * 128 + kt * 32 + quad * 8 + jj];
            }
            c += __shfl_xor(c, 16);
            c += __shfl_xor(c, 32);
            if (quad == 0) cs[hh * 64 + mt * 16 + lid] = c + sh;
        }
    }
    __syncthreads();   // cs visible

    f32x4 outacc[8];
    #pragma unroll
    for (int nt = 0; nt < 8; ++nt) outacc[nt] = z4;

    const int jc = j < NTOK ? j : NTOK - 1;
    const int aj = jc / 7, bj = jc - aj * 7;

    for (int h = hbase; h < hbase + NH; ++h) {
        // ======== stage A: T^T = G_h X (+r) — Gt rows hoisted, X from LDS ========
        {
            bf16x8 GA[2][4];
            #pragma unroll
            for (int mtl = 0; mtl < 2; ++mtl)
                #pragma unroll
                for (int kt = 0; kt < 4; ++kt)
                    GA[mtl][kt] = *(const bf16x8*)(Gt + h * 16384 + ((2 * w + mtl) * 16 + lid) * 128 + kt * 32 + quad * 8);
            #pragma unroll
            for (int nt = 0; nt < 4; ++nt) {
                bf16x8 xb[4];
                #pragma unroll
                for (int kt = 0; kt < 4; ++kt)
                    xb[kt] = *(const bf16x8*)(xw + swz128(nt * 16 + lid, kt * 32 + quad * 8));
                const int iT = nt * 16 + lid;
                #pragma unroll
                for (int mtl = 0; mtl < 2; ++mtl) {
                    f32x4 acc = z4;
                    #pragma unroll
                    for (int kt = 0; kt < 4; ++kt)
                        acc = __builtin_amdgcn_mfma_f32_16x16x32_bf16(GA[mtl][kt], xb[kt], acc, 0, 0, 0);
                    const int dpb = (2 * w + mtl) * 16 + quad * 4;
                    if (iT < NTOK) {   // garbage cols (stray-X) never stored
                        const f32x4 rb = *(const f32x4*)(rP + h * 128 + dpb);
                        u32x2 pkv;
                        pkv.x = pk2(acc[0] + rb[0], acc[1] + rb[1]);
                        pkv.y = pk2(acc[2] + rb[2], acc[3] + rb[3]);
                        *(u32x2*)(tsb + iT * 128 + ((((dpb >> 3) ^ (iT & 15)) & 15) << 3) + (dpb & 7)) = pkv;
                    }
                }
            }
        }
        // ======== stage A: U = X Wc_h^T (+bcv) — Wc rows hoisted, X from LDS ========
        {
            bf16x8 WB[2][4];
            float bb[2];
            #pragma unroll
            for (int ntl = 0; ntl < 2; ++ntl) {
                #pragma unroll
                for (int kt = 0; kt < 4; ++kt)
                    WB[ntl][kt] = *(const bf16x8*)(Wcw + h * 16384 + ((2 * w + ntl) * 16 + lid) * 128 + kt * 32 + quad * 8);
                bb[ntl] = bcv[h * 128 + (2 * w + ntl) * 16 + lid];
            }
            #pragma unroll
            for (int mt = 0; mt < 4; ++mt) {
                bf16x8 xa[4];
                #pragma unroll
                for (int kt = 0; kt < 4; ++kt) {
                    bf16x8 v = *(const bf16x8*)(xw + swz128(mt * 16 + lid, kt * 32 + quad * 8));
                    // mask token rows >= NTOK (stray LDS reads could be NaN; U rows
                    // >=49 meet P=0 in stage C and 0*NaN would poison)
                    xa[kt] = (mt < 3 || (mt * 16 + lid) < NTOK) ? v : zf;
                }
                const int ib = mt * 16 + quad * 4;
                #pragma unroll
                for (int ntl = 0; ntl < 2; ++ntl) {
                    f32x4 acc = z4;
                    #pragma unroll
                    for (int kt = 0; kt < 4; ++kt)
                        acc = __builtin_amdgcn_mfma_f32_16x16x32_bf16(xa[kt], WB[ntl][kt], acc, 0, 0, 0);
                    const int dd = (2 * w + ntl) * 16 + lid;
                    u32x2 pkv;
                    pkv.x = pk2(acc[0] + bb[ntl], acc[1] + bb[ntl]);
                    pkv.y = pk2(acc[2] + bb[ntl], acc[3] + bb[ntl]);
                    *(u32x2*)(usb + dd * 64 + ((((ib >> 3) ^ (dd & 7)) & 7) << 3) + (ib & 7)) = pkv;
                }
            }
        }
        __syncthreads();   // A done; B/C may read

        // ======== stage B: S = T X_j^T (+cs+pos), softmax, P write ========
        f32x4 S[4];
        #pragma unroll
        for (int mt = 0; mt < 4; ++mt) {
            S[mt] = z4;
            #pragma unroll
            for (int kt = 0; kt < 4; ++kt) {
                bf16x8 Abf = *(const bf16x8*)(tsb + (mt * 16 + lid) * 128 + ((((kt * 4 + quad) ^ lid) & 15) << 3));
                S[mt] = __builtin_amdgcn_mfma_f32_16x16x32_bf16(Abf, xown[kt], S[mt], 0, 0, 0);
            }
        }
        float sv[4][4];
        float mx = -3.0e38f;
        #pragma unroll
        for (int mt = 0; mt < 4; ++mt)
            #pragma unroll
            for (int r = 0; r < 4; ++r) {
                const int ii = mt * 16 + quad * 4 + r;
                float vvv;
                if (ii < NTOK) {
                    const int ai = ii / 7, bi = ii - ai * 7;
                    const int rel = (ai - aj + 6) + 13 * (bi - bj + 6);
                    vvv = S[mt][r] + cs[h * 64 + ii] + bf2f(pcf16[rel * NHEAD + h]);
                } else {
                    vvv = -3.0e38f;
                }
                sv[mt][r] = vvv;
                mx = fmaxf(mx, vvv);
            }
        mx = fmaxf(mx, __shfl_xor(mx, 16));
        mx = fmaxf(mx, __shfl_xor(mx, 32));
        float ssum = 0.f;
        #pragma unroll
        for (int mt = 0; mt < 4; ++mt)
            #pragma unroll
            for (int r = 0; r < 4; ++r) {
                const float e = __expf(sv[mt][r] - mx);
                sv[mt][r] = e;
                ssum += e;
            }
        ssum += __shfl_xor(ssum, 16);
        ssum += __shfl_xor(ssum, 32);
        const float inv = 1.0f / ssum;
        if (j < NTOK) {
            #pragma unroll
            for (int mt = 0; mt < 4; ++mt) {
                u32x2 pkv;
                pkv.x = pk2(sv[mt][0] * inv, sv[mt][1] * inv);
                pkv.y = pk2(sv[mt][2] * inv, sv[mt][3] * inv);
                *(u32x2*)(pl + j * PSTR + mt * 16 + quad * 4) = pkv;
            }
        }
        __threadfence_block();   // P rows wave-private: drain + no-reorder suffices

        // ======== stage C: outacc += P^T x U ========
        #pragma unroll
        for (int kt = 0; kt < 2; ++kt) {
            union { bf16x8 v; u32 u[4]; } Af;
            #pragma unroll
            for (int q2 = 0; q2 < 4; ++q2)
                Af.u[q2] = *(const u32*)(pl + jc * PSTR + kt * 32 + quad * 8 + 2 * q2);
            #pragma unroll
            for (int nt = 0; nt < 8; ++nt) {
                const int dd = nt * 16 + lid;
                bf16x8 Bu = *(const bf16x8*)(usb + dd * 64 + ((((kt * 4 + quad) ^ (dd & 7)) & 7) << 3));
                outacc[nt] = __builtin_amdgcn_mfma_f32_16x16x32_bf16(Af.v, Bu, outacc[nt], 0, 0, 0);
            }
        }
        if (h < hbase + NH - 1) __syncthreads();   // next head rewrites ts/us
    }

    // ======== epilogue ========
    float* pbuf = (hp == 1) ? part : out;
    float* outp = pbuf + n * DDIM * PTOT;
    const bool addb = (hbase == 0);
    #pragma unroll
    for (int nt = 0; nt < 8; ++nt) {
        const int dd = nt * 16 + lid;
        const float bov = addb ? bo[dd] : 0.0f;
        #pragma unroll
        for (int r = 0; r < 4; ++r) {
            const int jj = 16 * w + quad * 4 + r;
            if (jj < NTOK) {
                const int a = jj / 7, b = jj - a * 7;
                outp[dd * PTOT + pbase + a * CWID + b] = outacc[nt][r] + bov;
            }
        }
    }
}

// out += part (split mode)
__global__ void __launch_bounds__(256) addk(float* __restrict__ out,
                                            const float* __restrict__ part)
{
    const int N4 = NBATCH * DDIM * PTOT / 4;
    for (int i = blockIdx.x * 256 + threadIdx.x; i < N4; i += gridDim.x * 256) {
        f32x4 a = ((const f32x4*)out)[i];
        f32x4 b = ((const f32x4*)part)[i];
        a.x += b.x; a.y += b.y; a.z += b.z; a.w += b.w;
        ((f32x4*)out)[i] = a;
    }
}

extern "C" void kernel_launch(void* const* d_in, const int* in_sizes, int n_in,
                              void* d_out, int out_size, void* d_ws, size_t ws_size,
                              hipStream_t stream) {
    (void)in_sizes; (void)n_in; (void)out_size;
    prep<<<128, 256, 0, stream>>>((const float*)d_in[1], (const float*)d_in[3],
                                  (const float*)d_in[5], (const float*)d_in[7],
                                  (const float*)d_in[2], (const float*)d_in[4],
                                  (const float*)d_in[6], (u16*)d_ws);
    const size_t need = (size_t)WS_PART_BYTE + (size_t)OUT_BYTES;
    if (ws_size >= need) {
        float* part = (float*)((char*)d_ws + WS_PART_BYTE);
        winattn<<<NBATCH * 512, 256, 0, stream>>>(
            (const float*)d_in[0], (const u16*)d_ws,
            (const float*)d_in[8], (const float*)d_in[9],
            (float*)d_out, part, 1);
        addk<<<2048, 256, 0, stream>>>((float*)d_out, part);
    } else {
        winattn<<<NBATCH * 256, 256, 0, stream>>>(
            (const float*)d_in[0], (const u16*)d_ws,
            (const float*)d_in[8], (const float*)d_in[9],
            (float*)d_out, (float*)d_out, 0);
    }
}

// Round 6
// 268.397 us; speedup vs baseline: 1.7071x; 1.2021x over previous
//
#include <hip/hip_runtime.h>
#include <hip/hip_bf16.h>

typedef unsigned short u16;
typedef unsigned int u32;
typedef __attribute__((ext_vector_type(8))) short bf16x8;   // 8 bf16 = 4 VGPRs
typedef __attribute__((ext_vector_type(4))) float f32x4;
typedef __attribute__((ext_vector_type(2))) unsigned int u32x2;

#define NBATCH 4
#define DDIM   128
#define NHEAD  8
#define PTOT   12544
#define CWID   112     // patch grid width
#define NTOK   49      // tokens per 7x7 window
#define PSTR   68      // p_lds row stride (u16 elems)
#define SCALE  0.08838834764831845f

// Round-0 proven LDS layout (u16 units), double-buffered ts/us:
//   buf0: ts 64x128 @0, us 128x64 @8192 ; buf1 @16384 ; pl @32768 (49x68)
//   pcf f32[1352] @36100 ; cs f32[512] @38804 ; total 39828 u16 = 79656 B
// -> 2 blocks/CU (structural: register demand ~220 total caps waves/SIMD at 2
//    anyway; rounds 1/3/5 proved every higher-occupancy config spills).
#define BUFSZ   16384
#define OFF_US  8192
#define OFF_PL  32768
#define OFF_PCF 36100
#define OFF_CS  38804
#define LDS_TOT 39828

__device__ __forceinline__ float bf2f(u16 u) {
    union { u32 i; float f; } x; x.i = ((u32)u) << 16; return x.f;
}
__device__ __forceinline__ u16 f2bf(float f) {
    union { float f; u32 u; } v; v.f = f;
    return (u16)((v.u + 0x7fffu + ((v.u >> 16) & 1u)) >> 16);
}
__device__ __forceinline__ u32 pk2(float a, float b) {
    union { __hip_bfloat162 h; u32 u; } c;
    float2 t; t.x = a; t.y = b;
    c.h = __float22bfloat162_rn(t);
    return c.u;
}
__device__ __forceinline__ int swz128(int row, int col) {
    return row * 128 + ((((col >> 3) ^ (row & 15)) & 15) << 3) + (col & 7);
}

// ws layout: u16 Gt (8 x 128x128, pre-scaled) | u16 Wc (8 x 128x128) | fp32 block
// fp32 block at u16 offset 262144: bcv[1024] | r[1024] | M[1024] | s[8] (r/M/s scaled)
#define WS_WC   131072
#define WS_F32  262144

// ---- prepass (128 blocks = 16 outputs x 8 row-slices) ----
// b<8 -> Wc_h = Wo_h*Wv_h + bcv; b>=8 -> Gt_h = scaled (Wk^T Wq)^T + r/M/s
__global__ void __launch_bounds__(256) prep(
    const float* __restrict__ Wq, const float* __restrict__ Wk,
    const float* __restrict__ Wv, const float* __restrict__ Wo,
    const float* __restrict__ bq, const float* __restrict__ bk,
    const float* __restrict__ bv, u16* __restrict__ ws)
{
    __shared__ u16 lm[18432];           // A-slice 16x128 @0, B 128x128 @2048
    const int tid = threadIdx.x;
    const int bb  = blockIdx.x;
    const int b   = bb >> 3;
    const int sub = bb & 7;
    const bool isG = (b >= 8);
    const int h = b & 7;
    const int r0 = sub * 16;
    float* fb = (float*)(ws + WS_F32);

    if (!isG) {
        for (int idx = tid; idx < 2048; idx += 256) {
            const int lr = idx >> 7, dh = idx & 127;
            lm[swz128(lr, dh)] = f2bf(Wo[(r0 + lr) * 1024 + h * 128 + dh]);
        }
        for (int idx = tid; idx < 16384; idx += 256) {
            const int dh = idx >> 7, d = idx & 127;
            lm[2048 + swz128(d, dh)] = f2bf(Wv[(h * 128 + dh) * 128 + d]);
        }
        if (sub == 0 && tid < 128) {
            float s = 0.f;
            for (int dh = 0; dh < 128; ++dh)
                s += Wo[tid * 1024 + h * 128 + dh] * bv[h * 128 + dh];
            fb[h * 128 + tid] = s;                 // bcv
        }
    } else {
        for (int idx = tid; idx < 2048; idx += 256) {
            const int dh = idx >> 4, lr = idx & 15;
            lm[swz128(lr, dh)] = f2bf(Wk[(h * 128 + dh) * 128 + r0 + lr]);
        }
        for (int idx = tid; idx < 16384; idx += 256) {
            const int dh = idx >> 7, dp = idx & 127;
            lm[2048 + swz128(dp, dh)] = f2bf(Wq[(h * 128 + dh) * 128 + dp]);
        }
        if (sub == 0 && tid < 128) {
            float r = 0.f, m = 0.f;
            for (int dh = 0; dh < 128; ++dh) {
                r += bk[h * 128 + dh] * Wq[(h * 128 + dh) * 128 + tid];
                m += Wk[(h * 128 + dh) * 128 + tid] * bq[h * 128 + dh];
            }
            fb[1024 + h * 128 + tid] = r * SCALE;
            fb[2048 + h * 128 + tid] = m * SCALE;
        }
        if (sub == 0 && tid == 0) {
            float s = 0.f;
            for (int dh = 0; dh < 128; ++dh) s += bk[h * 128 + dh] * bq[h * 128 + dh];
            fb[3072 + h] = s * SCALE;
        }
    }
    __syncthreads();

    const int w = tid >> 6, lane = tid & 63, quad = lane >> 4, lid = lane & 15;
    const f32x4 z4 = {0.f, 0.f, 0.f, 0.f};
    u16* dst = ws + (isG ? 0 : WS_WC) + h * 16384;
    const float gs = isG ? SCALE : 1.0f;
    bf16x8 A[4];
    #pragma unroll
    for (int kt = 0; kt < 4; ++kt)
        A[kt] = *(const bf16x8*)(lm + swz128(lid, kt * 32 + quad * 8));
    #pragma unroll
    for (int ntl = 0; ntl < 2; ++ntl) {
        const int nt = 2 * w + ntl;
        f32x4 acc = z4;
        #pragma unroll
        for (int kt = 0; kt < 4; ++kt) {
            bf16x8 B = *(const bf16x8*)(lm + 2048 + swz128(nt * 16 + lid, kt * 32 + quad * 8));
            acc = __builtin_amdgcn_mfma_f32_16x16x32_bf16(A[kt], B, acc, 0, 0, 0);
        }
        #pragma unroll
        for (int r = 0; r < 4; ++r) {
            const int row = r0 + quad * 4 + r, col = nt * 16 + lid;
            if (isG) dst[col * 128 + row] = f2bf(acc[r] * gs);
            else     dst[row * 128 + col] = f2bf(acc[r]);
        }
    }
}

// stage B body, compile-time wave index WW so xfrag[WW] is a static register use
#define STAGE_B(WW) \
    _Pragma("unroll") \
    for (int mt = 0; mt < 4; ++mt) { \
        _Pragma("unroll") \
        for (int kt = 0; kt < 4; ++kt) { \
            bf16x8 Abf = *(const bf16x8*)(tsb + (mt * 16 + lid) * 128 + ((((kt * 4 + quad) ^ lid) & 15) << 3)); \
            S[mt] = __builtin_amdgcn_mfma_f32_16x16x32_bf16(Abf, xfrag[WW][kt], S[mt], 0, 0, 0); \
        } \
    }

// 256 threads = 4 waves; wave w owns query group j in [16w,16w+16).
// R0 structure (dbuf, 1 barrier/head) + grafts: cross-head Gt/Wc prefetch
// (issued right after the barrier, consumed next head — no intervening barrier
// so the loads stay in flight under B/softmax/C), xq removed (== xfrag[w]),
// softmax max-subtract removed (|logit| small -> exp safe, identical result).
__global__ void __launch_bounds__(256, 2)
winattn(const float* __restrict__ xg, const u16* __restrict__ ws,
        const float* __restrict__ bo, const float* __restrict__ posf,
        float* __restrict__ out)
{
    __shared__ __align__(16) u16 sm[LDS_TOT];
    u16* xw  = sm;                       // staging overlay on buf0 ts
    u16* pl  = sm + OFF_PL;              // P^T [j][i], wave-private rows
    float* pcf = (float*)(sm + OFF_PCF); // pos bias fp32
    float* cs  = (float*)(sm + OFF_CS);  // c_i per head

    const int tid  = threadIdx.x;
    const int w    = tid >> 6;
    const int lane = tid & 63;
    const int quad = lane >> 4;
    const int lid  = lane & 15;
    const int bx   = blockIdx.x;
    const int n    = bx >> 8;
    const int win  = bx & 255;
    const int pbase = (win >> 4) * 7 * CWID + (win & 15) * 7;

    const bf16x8 zf = {0,0,0,0,0,0,0,0};
    const f32x4  z4 = {0.f,0.f,0.f,0.f};

    const u16* Gt  = ws;
    const u16* Wcw = ws + WS_WC;
    const float* fb  = (const float*)(ws + WS_F32);
    const float* bcv = fb;
    const float* rP  = fb + 1024;
    const float* MP  = fb + 2048;
    const float* sP  = fb + 3072;

    // ---- stage pos table + x window ----
    for (int i = tid; i < 169 * NHEAD; i += 256) pcf[i] = posf[i];
    const float* xn = xg + n * DDIM * PTOT;
    for (int idx = tid; idx < DDIM * NTOK; idx += 256) {
        int d = idx / NTOK;
        int t = idx - d * NTOK;
        int a = t / 7, b = t - a * 7;
        xw[swz128(t, d)] = f2bf(xn[d * PTOT + pbase + a * CWID + b]);
    }
    __syncthreads();

    // ---- hoist x fragments (A-layout == B-layout: lane lid = token, quad*8 = d) ----
    bf16x8 xfrag[4][4];
    #pragma unroll
    for (int mt = 0; mt < 4; ++mt)
        #pragma unroll
        for (int kt = 0; kt < 4; ++kt)
            xfrag[mt][kt] = (mt * 16 + lid < NTOK)
                ? *(const bf16x8*)(xw + swz128(mt * 16 + lid, kt * 32 + quad * 8)) : zf;
    const int j = 16 * w + lid;

    // ---- weight fragments for head 0 (prefetched; c_i compute hides latency) ----
    bf16x8 GA[2][4], WB[2][4];
    {
        const int hh = 0;
        #pragma unroll
        for (int mtl = 0; mtl < 2; ++mtl)
            #pragma unroll
            for (int kt = 0; kt < 4; ++kt) {
                GA[mtl][kt] = *(const bf16x8*)(Gt  + hh * 16384 + ((2 * w + mtl) * 16 + lid) * 128 + kt * 32 + quad * 8);
                WB[mtl][kt] = *(const bf16x8*)(Wcw + hh * 16384 + ((2 * w + mtl) * 16 + lid) * 128 + kt * 32 + quad * 8);
            }
    }

    // ---- c_i tables (scaled): cs[h][i] = x_i . M_h + s_h ----
    for (int hh = w; hh < NHEAD; hh += 4) {
        const float sh = sP[hh];
        #pragma unroll
        for (int mt = 0; mt < 4; ++mt) {
            float c = 0.f;
            #pragma unroll
            for (int kt = 0; kt < 4; ++kt)
                #pragma unroll
                for (int jj = 0; jj < 8; ++jj)
                    c += bf2f((u16)xfrag[mt][kt][jj]) * MP[hh * 128 + kt * 32 + quad * 8 + jj];
            c += __shfl_xor(c, 16);
            c += __shfl_xor(c, 32);
            if (quad == 0) cs[hh * 64 + mt * 16 + lid] = c + sh;
        }
    }
    __syncthreads();   // xw dead (buffers overlay); cs visible

    f32x4 outacc[8];
    #pragma unroll
    for (int nt = 0; nt < 8; ++nt) outacc[nt] = z4;

    const int jc = j < NTOK ? j : NTOK - 1;
    const int aj = jc / 7, bj = jc - aj * 7;   // head-invariant

    #pragma unroll 2
    for (int h = 0; h < NHEAD; ++h) {
        u16* tsb = sm + (h & 1) * BUFSZ;            // T^T as ts[i][d'] swizzled
        u16* usb = tsb + OFF_US;                    // U as us[dd][i] swizzled

        // ======== stage A: T^T = G_h x X^T (+r) — prefetched GA ========
        #pragma unroll
        for (int mtl = 0; mtl < 2; ++mtl) {
            const int mt = 2 * w + mtl;             // d'-tile
            const f32x4 rb = *(const f32x4*)(rP + h * 128 + mt * 16 + quad * 4);
            const int dpb = mt * 16 + quad * 4;     // d' base for this lane's 4 outputs
            #pragma unroll
            for (int nt = 0; nt < 4; ++nt) {        // i-tiles
                f32x4 acc = z4;
                #pragma unroll
                for (int kt = 0; kt < 4; ++kt)
                    acc = __builtin_amdgcn_mfma_f32_16x16x32_bf16(GA[mtl][kt], xfrag[nt][kt], acc, 0, 0, 0);
                const int i = nt * 16 + lid;
                u32x2 pkv;
                pkv.x = pk2(acc[0] + rb[0], acc[1] + rb[1]);
                pkv.y = pk2(acc[2] + rb[2], acc[3] + rb[3]);
                *(u32x2*)(tsb + i * 128 + ((((dpb >> 3) ^ (i & 15)) & 15) << 3) + (dpb & 7)) = pkv;
            }
        }
        // ======== stage A: U = X x Wc_h^T (+bcv) — prefetched WB ========
        #pragma unroll
        for (int ntl = 0; ntl < 2; ++ntl) {
            const int nt = 2 * w + ntl;             // dd-tile
            const int dd = nt * 16 + lid;
            const float bb = bcv[h * 128 + dd];
            #pragma unroll
            for (int mt = 0; mt < 4; ++mt) {        // i-tiles
                f32x4 acc = z4;
                #pragma unroll
                for (int kt = 0; kt < 4; ++kt)
                    acc = __builtin_amdgcn_mfma_f32_16x16x32_bf16(xfrag[mt][kt], WB[ntl][kt], acc, 0, 0, 0);
                const int ib = mt * 16 + quad * 4;  // i base
                u32x2 pkv;
                pkv.x = pk2(acc[0] + bb, acc[1] + bb);
                pkv.y = pk2(acc[2] + bb, acc[3] + bb);
                *(u32x2*)(usb + dd * 64 + ((((ib >> 3) ^ (dd & 7)) & 7) << 3) + (ib & 7)) = pkv;
            }
        }
        __syncthreads();   // the ONLY block barrier per head

        // ---- prefetch next head's weights: in flight under B/softmax/C ----
        {
            const int hn = (h + 1) & 7;
            #pragma unroll
            for (int mtl = 0; mtl < 2; ++mtl)
                #pragma unroll
                for (int kt = 0; kt < 4; ++kt) {
                    GA[mtl][kt] = *(const bf16x8*)(Gt  + hn * 16384 + ((2 * w + mtl) * 16 + lid) * 128 + kt * 32 + quad * 8);
                    WB[mtl][kt] = *(const bf16x8*)(Wcw + hn * 16384 + ((2 * w + mtl) * 16 + lid) * 128 + kt * 32 + quad * 8);
                }
        }

        // ======== stage B: S = T x X_j^T (+cs+pos), softmax (no max-shift) ========
        f32x4 S[4];
        #pragma unroll
        for (int mt = 0; mt < 4; ++mt) S[mt] = z4;
        if      (w == 0) { STAGE_B(0) }
        else if (w == 1) { STAGE_B(1) }
        else if (w == 2) { STAGE_B(2) }
        else             { STAGE_B(3) }

        float sv[4][4];
        float ssum = 0.f;
        #pragma unroll
        for (int mt = 0; mt < 4; ++mt)
            #pragma unroll
            for (int r = 0; r < 4; ++r) {
                const int ii = mt * 16 + quad * 4 + r;
                float e;
                if (ii < NTOK) {
                    const int ai = ii / 7, bi = ii - ai * 7;
                    const int rel = (ai - aj + 6) + 13 * (bi - bj + 6);
                    e = __expf(S[mt][r] + cs[h * 64 + ii] + pcf[rel * NHEAD + h]);
                } else {
                    e = 0.0f;
                }
                sv[mt][r] = e;
                ssum += e;
            }
        ssum += __shfl_xor(ssum, 16);
        ssum += __shfl_xor(ssum, 32);
        const float inv = 1.0f / ssum;
        if (j < NTOK) {
            #pragma unroll
            for (int mt = 0; mt < 4; ++mt) {
                u32x2 pkv;
                pkv.x = pk2(sv[mt][0] * inv, sv[mt][1] * inv);
                pkv.y = pk2(sv[mt][2] * inv, sv[mt][3] * inv);
                *(u32x2*)(pl + j * PSTR + mt * 16 + quad * 4) = pkv;
            }
        }
        __threadfence_block();   // P rows wave-private: drain + no-reorder suffices

        // ======== stage C: outacc += P^T x U ========
        #pragma unroll
        for (int kt = 0; kt < 2; ++kt) {
            union { bf16x8 v; u32 u[4]; } Af;
            #pragma unroll
            for (int q2 = 0; q2 < 4; ++q2)
                Af.u[q2] = *(const u32*)(pl + jc * PSTR + kt * 32 + quad * 8 + 2 * q2);
            #pragma unroll
            for (int nt = 0; nt < 8; ++nt) {
                const int dd = nt * 16 + lid;
                bf16x8 Bu = *(const bf16x8*)(usb + dd * 64 + ((((kt * 4 + quad) ^ (dd & 7)) & 7) << 3));
                outacc[nt] = __builtin_amdgcn_mfma_f32_16x16x32_bf16(Af.v, Bu, outacc[nt], 0, 0, 0);
            }
        }
        // no end-of-head barrier: next head writes the OTHER ts/us buffer
    }

    // ======== epilogue: out[n][dd][p(j)] = acc + bo[dd]  (fp32 output) ========
    float* outp = out + n * DDIM * PTOT;
    #pragma unroll
    for (int nt = 0; nt < 8; ++nt) {
        const int dd = nt * 16 + lid;
        const float bov = bo[dd];
        #pragma unroll
        for (int r = 0; r < 4; ++r) {
            const int jj = 16 * w + quad * 4 + r;
            if (jj < NTOK) {
                const int a = jj / 7, b = jj - a * 7;
                outp[dd * PTOT + pbase + a * CWID + b] = outacc[nt][r] + bov;
            }
        }
    }
}

extern "C" void kernel_launch(void* const* d_in, const int* in_sizes, int n_in,
                              void* d_out, int out_size, void* d_ws, size_t ws_size,
                              hipStream_t stream) {
    (void)in_sizes; (void)n_in; (void)ws_size; (void)out_size;
    prep<<<128, 256, 0, stream>>>((const float*)d_in[1], (const float*)d_in[3],
                                  (const float*)d_in[5], (const float*)d_in[7],
                                  (const float*)d_in[2], (const float*)d_in[4],
                                  (const float*)d_in[6], (u16*)d_ws);
    winattn<<<NBATCH * 256, 256, 0, stream>>>(
        (const float*)d_in[0], (const u16*)d_ws,
        (const float*)d_in[8], (const float*)d_in[9], (float*)d_out);
}

// Round 7
// 227.105 us; speedup vs baseline: 2.0175x; 1.1818x over previous
//
#include <hip/hip_runtime.h>
#include <hip/hip_bf16.h>

typedef unsigned short u16;
typedef unsigned int u32;
typedef __attribute__((ext_vector_type(8))) short bf16x8;   // 8 bf16 = 4 VGPRs
typedef __attribute__((ext_vector_type(4))) float f32x4;
typedef __attribute__((ext_vector_type(2))) unsigned int u32x2;

#define NBATCH 4
#define DDIM   128
#define NHEAD  8
#define PTOT   12544
#define CWID   112     // patch grid width
#define NTOK   49      // tokens per 7x7 window
#define PSTR   68      // p_lds row stride (u16 elems)
#define SCALE  0.08838834764831845f

// Round-0 proven LDS layout (u16 units), double-buffered ts/us:
//   buf0: ts 64x128 @0, us 128x64 @8192 ; buf1 @16384 ; pl @32768 (49x68)
//   pcf f32[1352] @36100 ; cs f32[512] @38804 ; total 39828 u16 = 79656 B
// -> 2 blocks/CU. Register model (unified arch+AGPR, 256/wave at 2 waves/SIMD):
// R0 = 128 arch + 64 AGPR = 192. GA prefetch adds 32 -> ~224, still spill-free.
// R6 added GA+WB (+64) -> hit the 256 cap and spilled (WRITE 53->71 MB).
#define BUFSZ   16384
#define OFF_US  8192
#define OFF_PL  32768
#define OFF_PCF 36100
#define OFF_CS  38804
#define LDS_TOT 39828

__device__ __forceinline__ float bf2f(u16 u) {
    union { u32 i; float f; } x; x.i = ((u32)u) << 16; return x.f;
}
__device__ __forceinline__ u16 f2bf(float f) {
    union { float f; u32 u; } v; v.f = f;
    return (u16)((v.u + 0x7fffu + ((v.u >> 16) & 1u)) >> 16);
}
__device__ __forceinline__ u32 pk2(float a, float b) {
    union { __hip_bfloat162 h; u32 u; } c;
    float2 t; t.x = a; t.y = b;
    c.h = __float22bfloat162_rn(t);
    return c.u;
}
__device__ __forceinline__ int swz128(int row, int col) {
    return row * 128 + ((((col >> 3) ^ (row & 15)) & 15) << 3) + (col & 7);
}

// ws layout: u16 Gt (8 x 128x128, pre-scaled) | u16 Wc (8 x 128x128) | fp32 block
// fp32 block at u16 offset 262144: bcv[1024] | r[1024] | M[1024] | s[8] (r/M/s scaled)
#define WS_WC   131072
#define WS_F32  262144

// ---- prepass (128 blocks = 16 outputs x 8 row-slices) ----
// b<8 -> Wc_h = Wo_h*Wv_h + bcv; b>=8 -> Gt_h = scaled (Wk^T Wq)^T + r/M/s
__global__ void __launch_bounds__(256) prep(
    const float* __restrict__ Wq, const float* __restrict__ Wk,
    const float* __restrict__ Wv, const float* __restrict__ Wo,
    const float* __restrict__ bq, const float* __restrict__ bk,
    const float* __restrict__ bv, u16* __restrict__ ws)
{
    __shared__ u16 lm[18432];           // A-slice 16x128 @0, B 128x128 @2048
    const int tid = threadIdx.x;
    const int bb  = blockIdx.x;
    const int b   = bb >> 3;
    const int sub = bb & 7;
    const bool isG = (b >= 8);
    const int h = b & 7;
    const int r0 = sub * 16;
    float* fb = (float*)(ws + WS_F32);

    if (!isG) {
        for (int idx = tid; idx < 2048; idx += 256) {
            const int lr = idx >> 7, dh = idx & 127;
            lm[swz128(lr, dh)] = f2bf(Wo[(r0 + lr) * 1024 + h * 128 + dh]);
        }
        for (int idx = tid; idx < 16384; idx += 256) {
            const int dh = idx >> 7, d = idx & 127;
            lm[2048 + swz128(d, dh)] = f2bf(Wv[(h * 128 + dh) * 128 + d]);
        }
        if (sub == 0 && tid < 128) {
            float s = 0.f;
            for (int dh = 0; dh < 128; ++dh)
                s += Wo[tid * 1024 + h * 128 + dh] * bv[h * 128 + dh];
            fb[h * 128 + tid] = s;                 // bcv
        }
    } else {
        for (int idx = tid; idx < 2048; idx += 256) {
            const int dh = idx >> 4, lr = idx & 15;
            lm[swz128(lr, dh)] = f2bf(Wk[(h * 128 + dh) * 128 + r0 + lr]);
        }
        for (int idx = tid; idx < 16384; idx += 256) {
            const int dh = idx >> 7, dp = idx & 127;
            lm[2048 + swz128(dp, dh)] = f2bf(Wq[(h * 128 + dh) * 128 + dp]);
        }
        if (sub == 0 && tid < 128) {
            float r = 0.f, m = 0.f;
            for (int dh = 0; dh < 128; ++dh) {
                r += bk[h * 128 + dh] * Wq[(h * 128 + dh) * 128 + tid];
                m += Wk[(h * 128 + dh) * 128 + tid] * bq[h * 128 + dh];
            }
            fb[1024 + h * 128 + tid] = r * SCALE;
            fb[2048 + h * 128 + tid] = m * SCALE;
        }
        if (sub == 0 && tid == 0) {
            float s = 0.f;
            for (int dh = 0; dh < 128; ++dh) s += bk[h * 128 + dh] * bq[h * 128 + dh];
            fb[3072 + h] = s * SCALE;
        }
    }
    __syncthreads();

    const int w = tid >> 6, lane = tid & 63, quad = lane >> 4, lid = lane & 15;
    const f32x4 z4 = {0.f, 0.f, 0.f, 0.f};
    u16* dst = ws + (isG ? 0 : WS_WC) + h * 16384;
    const float gs = isG ? SCALE : 1.0f;
    bf16x8 A[4];
    #pragma unroll
    for (int kt = 0; kt < 4; ++kt)
        A[kt] = *(const bf16x8*)(lm + swz128(lid, kt * 32 + quad * 8));
    #pragma unroll
    for (int ntl = 0; ntl < 2; ++ntl) {
        const int nt = 2 * w + ntl;
        f32x4 acc = z4;
        #pragma unroll
        for (int kt = 0; kt < 4; ++kt) {
            bf16x8 B = *(const bf16x8*)(lm + 2048 + swz128(nt * 16 + lid, kt * 32 + quad * 8));
            acc = __builtin_amdgcn_mfma_f32_16x16x32_bf16(A[kt], B, acc, 0, 0, 0);
        }
        #pragma unroll
        for (int r = 0; r < 4; ++r) {
            const int row = r0 + quad * 4 + r, col = nt * 16 + lid;
            if (isG) dst[col * 128 + row] = f2bf(acc[r] * gs);
            else     dst[row * 128 + col] = f2bf(acc[r]);
        }
    }
}

// stage B body, compile-time wave index WW so xfrag[WW] is a static register use
#define STAGE_B(WW) \
    _Pragma("unroll") \
    for (int mt = 0; mt < 4; ++mt) { \
        _Pragma("unroll") \
        for (int kt = 0; kt < 4; ++kt) { \
            bf16x8 Abf = *(const bf16x8*)(tsb + (mt * 16 + lid) * 128 + ((((kt * 4 + quad) ^ lid) & 15) << 3)); \
            S[mt] = __builtin_amdgcn_mfma_f32_16x16x32_bf16(Abf, xfrag[WW][kt], S[mt], 0, 0, 0); \
        } \
    }

// 256 threads = 4 waves; wave w owns query group j in [16w,16w+16).
// R0 structure (dbuf, 1 barrier/head) + verified grafts: GA-only cross-head
// prefetch (+32 regs, fits the 256 budget), no-max softmax, xq==xfrag[w].
__global__ void __launch_bounds__(256, 2)
winattn(const float* __restrict__ xg, const u16* __restrict__ ws,
        const float* __restrict__ bo, const float* __restrict__ posf,
        float* __restrict__ out)
{
    __shared__ __align__(16) u16 sm[LDS_TOT];
    u16* xw  = sm;                       // staging overlay on buf0 ts
    u16* pl  = sm + OFF_PL;              // P^T [j][i], wave-private rows
    float* pcf = (float*)(sm + OFF_PCF); // pos bias fp32
    float* cs  = (float*)(sm + OFF_CS);  // c_i per head

    const int tid  = threadIdx.x;
    const int w    = tid >> 6;
    const int lane = tid & 63;
    const int quad = lane >> 4;
    const int lid  = lane & 15;
    const int bx   = blockIdx.x;
    const int n    = bx >> 8;
    const int win  = bx & 255;
    const int pbase = (win >> 4) * 7 * CWID + (win & 15) * 7;

    const bf16x8 zf = {0,0,0,0,0,0,0,0};
    const f32x4  z4 = {0.f,0.f,0.f,0.f};

    const u16* Gt  = ws;
    const u16* Wcw = ws + WS_WC;
    const float* fb  = (const float*)(ws + WS_F32);
    const float* bcv = fb;
    const float* rP  = fb + 1024;
    const float* MP  = fb + 2048;
    const float* sP  = fb + 3072;

    // ---- stage pos table + x window ----
    for (int i = tid; i < 169 * NHEAD; i += 256) pcf[i] = posf[i];
    const float* xn = xg + n * DDIM * PTOT;
    for (int idx = tid; idx < DDIM * NTOK; idx += 256) {
        int d = idx / NTOK;
        int t = idx - d * NTOK;
        int a = t / 7, b = t - a * 7;
        xw[swz128(t, d)] = f2bf(xn[d * PTOT + pbase + a * CWID + b]);
    }
    __syncthreads();

    // ---- hoist x fragments (A-layout == B-layout: lane lid = token, quad*8 = d) ----
    bf16x8 xfrag[4][4];
    #pragma unroll
    for (int mt = 0; mt < 4; ++mt)
        #pragma unroll
        for (int kt = 0; kt < 4; ++kt)
            xfrag[mt][kt] = (mt * 16 + lid < NTOK)
                ? *(const bf16x8*)(xw + swz128(mt * 16 + lid, kt * 32 + quad * 8)) : zf;
    const int j = 16 * w + lid;

    // ---- GA fragments for head 0 (prefetched; c_i compute hides latency) ----
    bf16x8 GA[2][4];
    #pragma unroll
    for (int mtl = 0; mtl < 2; ++mtl)
        #pragma unroll
        for (int kt = 0; kt < 4; ++kt)
            GA[mtl][kt] = *(const bf16x8*)(Gt + ((2 * w + mtl) * 16 + lid) * 128 + kt * 32 + quad * 8);

    // ---- c_i tables (scaled): cs[h][i] = x_i . M_h + s_h ----
    for (int hh = w; hh < NHEAD; hh += 4) {
        const float sh = sP[hh];
        #pragma unroll
        for (int mt = 0; mt < 4; ++mt) {
            float c = 0.f;
            #pragma unroll
            for (int kt = 0; kt < 4; ++kt)
                #pragma unroll
                for (int jj = 0; jj < 8; ++jj)
                    c += bf2f((u16)xfrag[mt][kt][jj]) * MP[hh * 128 + kt * 32 + quad * 8 + jj];
            c += __shfl_xor(c, 16);
            c += __shfl_xor(c, 32);
            if (quad == 0) cs[hh * 64 + mt * 16 + lid] = c + sh;
        }
    }
    __syncthreads();   // xw dead (buffers overlay); cs visible

    f32x4 outacc[8];
    #pragma unroll
    for (int nt = 0; nt < 8; ++nt) outacc[nt] = z4;

    const int jc = j < NTOK ? j : NTOK - 1;
    const int aj = jc / 7, bj = jc - aj * 7;   // head-invariant

    #pragma unroll 2
    for (int h = 0; h < NHEAD; ++h) {
        u16* tsb = sm + (h & 1) * BUFSZ;            // T^T as ts[i][d'] swizzled
        u16* usb = tsb + OFF_US;                    // U as us[dd][i] swizzled

        // ======== stage A: T^T = G_h x X^T (+r) — prefetched GA ========
        #pragma unroll
        for (int mtl = 0; mtl < 2; ++mtl) {
            const int mt = 2 * w + mtl;             // d'-tile
            const f32x4 rb = *(const f32x4*)(rP + h * 128 + mt * 16 + quad * 4);
            const int dpb = mt * 16 + quad * 4;     // d' base for this lane's 4 outputs
            #pragma unroll
            for (int nt = 0; nt < 4; ++nt) {        // i-tiles
                f32x4 acc = z4;
                #pragma unroll
                for (int kt = 0; kt < 4; ++kt)
                    acc = __builtin_amdgcn_mfma_f32_16x16x32_bf16(GA[mtl][kt], xfrag[nt][kt], acc, 0, 0, 0);
                const int i = nt * 16 + lid;
                u32x2 pkv;
                pkv.x = pk2(acc[0] + rb[0], acc[1] + rb[1]);
                pkv.y = pk2(acc[2] + rb[2], acc[3] + rb[3]);
                *(u32x2*)(tsb + i * 128 + ((((dpb >> 3) ^ (i & 15)) & 15) << 3) + (dpb & 7)) = pkv;
            }
        }
        // ======== stage A: U = X x Wc_h^T (+bcv) — WB loaded in place (R0) ========
        #pragma unroll
        for (int ntl = 0; ntl < 2; ++ntl) {
            const int nt = 2 * w + ntl;             // dd-tile
            bf16x8 B[4];
            #pragma unroll
            for (int kt = 0; kt < 4; ++kt)
                B[kt] = *(const bf16x8*)(Wcw + h * 16384 + (nt * 16 + lid) * 128 + kt * 32 + quad * 8);
            const int dd = nt * 16 + lid;
            const float bb = bcv[h * 128 + dd];
            #pragma unroll
            for (int mt = 0; mt < 4; ++mt) {        // i-tiles
                f32x4 acc = z4;
                #pragma unroll
                for (int kt = 0; kt < 4; ++kt)
                    acc = __builtin_amdgcn_mfma_f32_16x16x32_bf16(xfrag[mt][kt], B[kt], acc, 0, 0, 0);
                const int ib = mt * 16 + quad * 4;  // i base
                u32x2 pkv;
                pkv.x = pk2(acc[0] + bb, acc[1] + bb);
                pkv.y = pk2(acc[2] + bb, acc[3] + bb);
                *(u32x2*)(usb + dd * 64 + ((((ib >> 3) ^ (dd & 7)) & 7) << 3) + (ib & 7)) = pkv;
            }
        }
        __syncthreads();   // the ONLY block barrier per head

        // ---- prefetch next head's GA: in flight under B/softmax/C ----
        {
            const int hn = (h + 1) & 7;
            #pragma unroll
            for (int mtl = 0; mtl < 2; ++mtl)
                #pragma unroll
                for (int kt = 0; kt < 4; ++kt)
                    GA[mtl][kt] = *(const bf16x8*)(Gt + hn * 16384 + ((2 * w + mtl) * 16 + lid) * 128 + kt * 32 + quad * 8);
        }

        // ======== stage B: S = T x X_j^T (+cs+pos), softmax (no max-shift) ========
        f32x4 S[4];
        #pragma unroll
        for (int mt = 0; mt < 4; ++mt) S[mt] = z4;
        if      (w == 0) { STAGE_B(0) }
        else if (w == 1) { STAGE_B(1) }
        else if (w == 2) { STAGE_B(2) }
        else             { STAGE_B(3) }

        float sv[4][4];
        float ssum = 0.f;
        #pragma unroll
        for (int mt = 0; mt < 4; ++mt)
            #pragma unroll
            for (int r = 0; r < 4; ++r) {
                const int ii = mt * 16 + quad * 4 + r;
                float e;
                if (ii < NTOK) {
                    const int ai = ii / 7, bi = ii - ai * 7;
                    const int rel = (ai - aj + 6) + 13 * (bi - bj + 6);
                    e = __expf(S[mt][r] + cs[h * 64 + ii] + pcf[rel * NHEAD + h]);
                } else {
                    e = 0.0f;
                }
                sv[mt][r] = e;
                ssum += e;
            }
        ssum += __shfl_xor(ssum, 16);
        ssum += __shfl_xor(ssum, 32);
        const float inv = 1.0f / ssum;
        if (j < NTOK) {
            #pragma unroll
            for (int mt = 0; mt < 4; ++mt) {
                u32x2 pkv;
                pkv.x = pk2(sv[mt][0] * inv, sv[mt][1] * inv);
                pkv.y = pk2(sv[mt][2] * inv, sv[mt][3] * inv);
                *(u32x2*)(pl + j * PSTR + mt * 16 + quad * 4) = pkv;
            }
        }
        __threadfence_block();   // P rows wave-private: drain + no-reorder suffices

        // ======== stage C: outacc += P^T x U ========
        #pragma unroll
        for (int kt = 0; kt < 2; ++kt) {
            union { bf16x8 v; u32 u[4]; } Af;
            #pragma unroll
            for (int q2 = 0; q2 < 4; ++q2)
                Af.u[q2] = *(const u32*)(pl + jc * PSTR + kt * 32 + quad * 8 + 2 * q2);
            #pragma unroll
            for (int nt = 0; nt < 8; ++nt) {
                const int dd = nt * 16 + lid;
                bf16x8 Bu = *(const bf16x8*)(usb + dd * 64 + ((((kt * 4 + quad) ^ (dd & 7)) & 7) << 3));
                outacc[nt] = __builtin_amdgcn_mfma_f32_16x16x32_bf16(Af.v, Bu, outacc[nt], 0, 0, 0);
            }
        }
        // no end-of-head barrier: next head writes the OTHER ts/us buffer
    }

    // ======== epilogue: out[n][dd][p(j)] = acc + bo[dd]  (fp32 output) ========
    float* outp = out + n * DDIM * PTOT;
    #pragma unroll
    for (int nt = 0; nt < 8; ++nt) {
        const int dd = nt * 16 + lid;
        const float bov = bo[dd];
        #pragma unroll
        for (int r = 0; r < 4; ++r) {
            const int jj = 16 * w + quad * 4 + r;
            if (jj < NTOK) {
                const int a = jj / 7, b = jj - a * 7;
                outp[dd * PTOT + pbase + a * CWID + b] = outacc[nt][r] + bov;
            }
        }
    }
}

extern "C" void kernel_launch(void* const* d_in, const int* in_sizes, int n_in,
                              void* d_out, int out_size, void* d_ws, size_t ws_size,
                              hipStream_t stream) {
    (void)in_sizes; (void)n_in; (void)ws_size; (void)out_size;
    prep<<<128, 256, 0, stream>>>((const float*)d_in[1], (const float*)d_in[3],
                                  (const float*)d_in[5], (const float*)d_in[7],
                                  (const float*)d_in[2], (const float*)d_in[4],
                                  (const float*)d_in[6], (u16*)d_ws);
    winattn<<<NBATCH * 256, 256, 0, stream>>>(
        (const float*)d_in[0], (const u16*)d_ws,
        (const float*)d_in[8], (const float*)d_in[9], (float*)d_out);
}

// Round 8
// 220.779 us; speedup vs baseline: 2.0753x; 1.0287x over previous
//
#include <hip/hip_runtime.h>
#include <hip/hip_bf16.h>

typedef unsigned short u16;
typedef unsigned int u32;
typedef __attribute__((ext_vector_type(8))) short bf16x8;   // 8 bf16 = 4 VGPRs
typedef __attribute__((ext_vector_type(4))) float f32x4;
typedef __attribute__((ext_vector_type(2))) unsigned int u32x2;

#define NBATCH 4
#define DDIM   128
#define NHEAD  8
#define PTOT   12544
#define CWID   112     // patch grid width
#define NTOK   49      // tokens per 7x7 window
#define PSTR   68      // p_lds row stride (u16 elems)
#define SCALE  0.08838834764831845f

// Round-0 proven LDS layout (u16 units), double-buffered ts/us:
//   buf0: ts 64x128 @0, us 128x64 @8192 ; buf1 @16384 ; pl @32768 (49x68)
//   pcf f32[1352] @36100 ; cs f32[512] @38804 ; total 39828 u16 = 79656 B
// -> 2 blocks/CU, 2 waves/SIMD (structural; accepted).
// Register model: R7 = xfrag64 + outacc32A + GA32 + live ~192-224, no spill.
// WB(h+1) prefetch is issued AFTER the P-write so its live range covers only
// stage C (S/sv dead there): peak ~200 < 256. R6 (WB live across B/SM) spilled.
#define BUFSZ   16384
#define OFF_US  8192
#define OFF_PL  32768
#define OFF_PCF 36100
#define OFF_CS  38804
#define LDS_TOT 39828

__device__ __forceinline__ float bf2f(u16 u) {
    union { u32 i; float f; } x; x.i = ((u32)u) << 16; return x.f;
}
__device__ __forceinline__ u16 f2bf(float f) {
    union { float f; u32 u; } v; v.f = f;
    return (u16)((v.u + 0x7fffu + ((v.u >> 16) & 1u)) >> 16);
}
__device__ __forceinline__ u32 pk2(float a, float b) {
    union { __hip_bfloat162 h; u32 u; } c;
    float2 t; t.x = a; t.y = b;
    c.h = __float22bfloat162_rn(t);
    return c.u;
}
__device__ __forceinline__ int swz128(int row, int col) {
    return row * 128 + ((((col >> 3) ^ (row & 15)) & 15) << 3) + (col & 7);
}

// ws layout: u16 Gt (8 x 128x128, pre-scaled) | u16 Wc (8 x 128x128) | fp32 block
// fp32 block at u16 offset 262144: bcv[1024] | r[1024] | M[1024] | s[8] (r/M/s scaled)
#define WS_WC   131072
#define WS_F32  262144

// ---- prepass (128 blocks = 16 outputs x 8 row-slices) ----
// b<8 -> Wc_h = Wo_h*Wv_h + bcv; b>=8 -> Gt_h = scaled (Wk^T Wq)^T + r/M/s
__global__ void __launch_bounds__(256) prep(
    const float* __restrict__ Wq, const float* __restrict__ Wk,
    const float* __restrict__ Wv, const float* __restrict__ Wo,
    const float* __restrict__ bq, const float* __restrict__ bk,
    const float* __restrict__ bv, u16* __restrict__ ws)
{
    __shared__ u16 lm[18432];           // A-slice 16x128 @0, B 128x128 @2048
    const int tid = threadIdx.x;
    const int bb  = blockIdx.x;
    const int b   = bb >> 3;
    const int sub = bb & 7;
    const bool isG = (b >= 8);
    const int h = b & 7;
    const int r0 = sub * 16;
    float* fb = (float*)(ws + WS_F32);

    if (!isG) {
        for (int idx = tid; idx < 2048; idx += 256) {
            const int lr = idx >> 7, dh = idx & 127;
            lm[swz128(lr, dh)] = f2bf(Wo[(r0 + lr) * 1024 + h * 128 + dh]);
        }
        for (int idx = tid; idx < 16384; idx += 256) {
            const int dh = idx >> 7, d = idx & 127;
            lm[2048 + swz128(d, dh)] = f2bf(Wv[(h * 128 + dh) * 128 + d]);
        }
        if (sub == 0 && tid < 128) {
            float s = 0.f;
            for (int dh = 0; dh < 128; ++dh)
                s += Wo[tid * 1024 + h * 128 + dh] * bv[h * 128 + dh];
            fb[h * 128 + tid] = s;                 // bcv
        }
    } else {
        for (int idx = tid; idx < 2048; idx += 256) {
            const int dh = idx >> 4, lr = idx & 15;
            lm[swz128(lr, dh)] = f2bf(Wk[(h * 128 + dh) * 128 + r0 + lr]);
        }
        for (int idx = tid; idx < 16384; idx += 256) {
            const int dh = idx >> 7, dp = idx & 127;
            lm[2048 + swz128(dp, dh)] = f2bf(Wq[(h * 128 + dh) * 128 + dp]);
        }
        if (sub == 0 && tid < 128) {
            float r = 0.f, m = 0.f;
            for (int dh = 0; dh < 128; ++dh) {
                r += bk[h * 128 + dh] * Wq[(h * 128 + dh) * 128 + tid];
                m += Wk[(h * 128 + dh) * 128 + tid] * bq[h * 128 + dh];
            }
            fb[1024 + h * 128 + tid] = r * SCALE;
            fb[2048 + h * 128 + tid] = m * SCALE;
        }
        if (sub == 0 && tid == 0) {
            float s = 0.f;
            for (int dh = 0; dh < 128; ++dh) s += bk[h * 128 + dh] * bq[h * 128 + dh];
            fb[3072 + h] = s * SCALE;
        }
    }
    __syncthreads();

    const int w = tid >> 6, lane = tid & 63, quad = lane >> 4, lid = lane & 15;
    const f32x4 z4 = {0.f, 0.f, 0.f, 0.f};
    u16* dst = ws + (isG ? 0 : WS_WC) + h * 16384;
    const float gs = isG ? SCALE : 1.0f;
    bf16x8 A[4];
    #pragma unroll
    for (int kt = 0; kt < 4; ++kt)
        A[kt] = *(const bf16x8*)(lm + swz128(lid, kt * 32 + quad * 8));
    #pragma unroll
    for (int ntl = 0; ntl < 2; ++ntl) {
        const int nt = 2 * w + ntl;
        f32x4 acc = z4;
        #pragma unroll
        for (int kt = 0; kt < 4; ++kt) {
            bf16x8 B = *(const bf16x8*)(lm + 2048 + swz128(nt * 16 + lid, kt * 32 + quad * 8));
            acc = __builtin_amdgcn_mfma_f32_16x16x32_bf16(A[kt], B, acc, 0, 0, 0);
        }
        #pragma unroll
        for (int r = 0; r < 4; ++r) {
            const int row = r0 + quad * 4 + r, col = nt * 16 + lid;
            if (isG) dst[col * 128 + row] = f2bf(acc[r] * gs);
            else     dst[row * 128 + col] = f2bf(acc[r]);
        }
    }
}

// stage B body, compile-time wave index WW so xfrag[WW] is a static register use
#define STAGE_B(WW) \
    _Pragma("unroll") \
    for (int mt = 0; mt < 4; ++mt) { \
        _Pragma("unroll") \
        for (int kt = 0; kt < 4; ++kt) { \
            bf16x8 Abf = *(const bf16x8*)(tsb + (mt * 16 + lid) * 128 + ((((kt * 4 + quad) ^ lid) & 15) << 3)); \
            S[mt] = __builtin_amdgcn_mfma_f32_16x16x32_bf16(Abf, xfrag[WW][kt], S[mt], 0, 0, 0); \
        } \
    }

// 256 threads = 4 waves; wave w owns query group j in [16w,16w+16).
// R7 + grafts: WB(h+1) prefetch after P-write (live over C only), lgkmcnt-only
// fence (keeps WB/GA loads in flight), XCD-swizzled block mapping (2 window-rows
// per XCD -> x/out cacheline dedup in L2), setprio around MFMA clusters.
__global__ void __launch_bounds__(256, 2)
winattn(const float* __restrict__ xg, const u16* __restrict__ ws,
        const float* __restrict__ bo, const float* __restrict__ posf,
        float* __restrict__ out)
{
    __shared__ __align__(16) u16 sm[LDS_TOT];
    u16* xw  = sm;                       // staging overlay on buf0 ts
    u16* pl  = sm + OFF_PL;              // P^T [j][i], wave-private rows
    float* pcf = (float*)(sm + OFF_PCF); // pos bias fp32
    float* cs  = (float*)(sm + OFF_CS);  // c_i per head

    const int tid  = threadIdx.x;
    const int w    = tid >> 6;
    const int lane = tid & 63;
    const int quad = lane >> 4;
    const int lid  = lane & 15;
    // XCD-aware bijective remap: xcd = bx&7 gets 32 consecutive windows
    // (2 full 16-window rows) for each n -> shared x/out cachelines stay in
    // one XCD's L2 instead of being re-fetched by 8 XCDs.
    const int bx0  = blockIdx.x;
    const int xcd  = bx0 & 7;
    const int idx0 = bx0 >> 3;
    const int n    = idx0 >> 5;
    const int win  = xcd * 32 + (idx0 & 31);
    const int pbase = (win >> 4) * 7 * CWID + (win & 15) * 7;

    const bf16x8 zf = {0,0,0,0,0,0,0,0};
    const f32x4  z4 = {0.f,0.f,0.f,0.f};

    const u16* Gt  = ws;
    const u16* Wcw = ws + WS_WC;
    const float* fb  = (const float*)(ws + WS_F32);
    const float* bcv = fb;
    const float* rP  = fb + 1024;
    const float* MP  = fb + 2048;
    const float* sP  = fb + 3072;

    // ---- stage pos table + x window ----
    for (int i = tid; i < 169 * NHEAD; i += 256) pcf[i] = posf[i];
    const float* xn = xg + n * DDIM * PTOT;
    for (int idx = tid; idx < DDIM * NTOK; idx += 256) {
        int d = idx / NTOK;
        int t = idx - d * NTOK;
        int a = t / 7, b = t - a * 7;
        xw[swz128(t, d)] = f2bf(xn[d * PTOT + pbase + a * CWID + b]);
    }
    __syncthreads();

    // ---- hoist x fragments (A-layout == B-layout: lane lid = token, quad*8 = d) ----
    bf16x8 xfrag[4][4];
    #pragma unroll
    for (int mt = 0; mt < 4; ++mt)
        #pragma unroll
        for (int kt = 0; kt < 4; ++kt)
            xfrag[mt][kt] = (mt * 16 + lid < NTOK)
                ? *(const bf16x8*)(xw + swz128(mt * 16 + lid, kt * 32 + quad * 8)) : zf;
    const int j = 16 * w + lid;

    // ---- head-0 weights prefetched; c_i compute hides their latency ----
    bf16x8 GA[2][4], WBn[2][4];
    #pragma unroll
    for (int mtl = 0; mtl < 2; ++mtl)
        #pragma unroll
        for (int kt = 0; kt < 4; ++kt) {
            GA[mtl][kt]  = *(const bf16x8*)(Gt  + ((2 * w + mtl) * 16 + lid) * 128 + kt * 32 + quad * 8);
            WBn[mtl][kt] = *(const bf16x8*)(Wcw + ((2 * w + mtl) * 16 + lid) * 128 + kt * 32 + quad * 8);
        }

    // ---- c_i tables (scaled): cs[h][i] = x_i . M_h + s_h ----
    for (int hh = w; hh < NHEAD; hh += 4) {
        const float sh = sP[hh];
        #pragma unroll
        for (int mt = 0; mt < 4; ++mt) {
            float c = 0.f;
            #pragma unroll
            for (int kt = 0; kt < 4; ++kt)
                #pragma unroll
                for (int jj = 0; jj < 8; ++jj)
                    c += bf2f((u16)xfrag[mt][kt][jj]) * MP[hh * 128 + kt * 32 + quad * 8 + jj];
            c += __shfl_xor(c, 16);
            c += __shfl_xor(c, 32);
            if (quad == 0) cs[hh * 64 + mt * 16 + lid] = c + sh;
        }
    }
    __syncthreads();   // xw dead (buffers overlay); cs visible

    f32x4 outacc[8];
    #pragma unroll
    for (int nt = 0; nt < 8; ++nt) outacc[nt] = z4;

    const int jc = j < NTOK ? j : NTOK - 1;
    const int aj = jc / 7, bj = jc - aj * 7;   // head-invariant

    #pragma unroll 2
    for (int h = 0; h < NHEAD; ++h) {
        u16* tsb = sm + (h & 1) * BUFSZ;            // T^T as ts[i][d'] swizzled
        u16* usb = tsb + OFF_US;                    // U as us[dd][i] swizzled

        __builtin_amdgcn_s_setprio(1);
        // ======== stage A: T^T = G_h x X^T (+r) — prefetched GA ========
        #pragma unroll
        for (int mtl = 0; mtl < 2; ++mtl) {
            const int mt = 2 * w + mtl;             // d'-tile
            const f32x4 rb = *(const f32x4*)(rP + h * 128 + mt * 16 + quad * 4);
            const int dpb = mt * 16 + quad * 4;     // d' base for this lane's 4 outputs
            #pragma unroll
            for (int nt = 0; nt < 4; ++nt) {        // i-tiles
                f32x4 acc = z4;
                #pragma unroll
                for (int kt = 0; kt < 4; ++kt)
                    acc = __builtin_amdgcn_mfma_f32_16x16x32_bf16(GA[mtl][kt], xfrag[nt][kt], acc, 0, 0, 0);
                const int i = nt * 16 + lid;
                u32x2 pkv;
                pkv.x = pk2(acc[0] + rb[0], acc[1] + rb[1]);
                pkv.y = pk2(acc[2] + rb[2], acc[3] + rb[3]);
                *(u32x2*)(tsb + i * 128 + ((((dpb >> 3) ^ (i & 15)) & 15) << 3) + (dpb & 7)) = pkv;
            }
        }
        // ======== stage A: U = X x Wc_h^T (+bcv) — prefetched WBn ========
        #pragma unroll
        for (int ntl = 0; ntl < 2; ++ntl) {
            const int nt = 2 * w + ntl;             // dd-tile
            const int dd = nt * 16 + lid;
            const float bb = bcv[h * 128 + dd];
            #pragma unroll
            for (int mt = 0; mt < 4; ++mt) {        // i-tiles
                f32x4 acc = z4;
                #pragma unroll
                for (int kt = 0; kt < 4; ++kt)
                    acc = __builtin_amdgcn_mfma_f32_16x16x32_bf16(xfrag[mt][kt], WBn[ntl][kt], acc, 0, 0, 0);
                const int ib = mt * 16 + quad * 4;  // i base
                u32x2 pkv;
                pkv.x = pk2(acc[0] + bb, acc[1] + bb);
                pkv.y = pk2(acc[2] + bb, acc[3] + bb);
                *(u32x2*)(usb + dd * 64 + ((((ib >> 3) ^ (dd & 7)) & 7) << 3) + (ib & 7)) = pkv;
            }
        }
        __builtin_amdgcn_s_setprio(0);
        __syncthreads();   // the ONLY block barrier per head

        // ---- prefetch next head's GA: in flight under B/softmax ----
        {
            const int hn = (h + 1) & 7;
            #pragma unroll
            for (int mtl = 0; mtl < 2; ++mtl)
                #pragma unroll
                for (int kt = 0; kt < 4; ++kt)
                    GA[mtl][kt] = *(const bf16x8*)(Gt + hn * 16384 + ((2 * w + mtl) * 16 + lid) * 128 + kt * 32 + quad * 8);
        }

        // ======== stage B: S = T x X_j^T (+cs+pos), softmax (no max-shift) ========
        f32x4 S[4];
        #pragma unroll
        for (int mt = 0; mt < 4; ++mt) S[mt] = z4;
        __builtin_amdgcn_s_setprio(1);
        if      (w == 0) { STAGE_B(0) }
        else if (w == 1) { STAGE_B(1) }
        else if (w == 2) { STAGE_B(2) }
        else             { STAGE_B(3) }
        __builtin_amdgcn_s_setprio(0);

        float sv[4][4];
        float ssum = 0.f;
        #pragma unroll
        for (int mt = 0; mt < 4; ++mt)
            #pragma unroll
            for (int r = 0; r < 4; ++r) {
                const int ii = mt * 16 + quad * 4 + r;
                float e;
                if (ii < NTOK) {
                    const int ai = ii / 7, bi = ii - ai * 7;
                    const int rel = (ai - aj + 6) + 13 * (bi - bj + 6);
                    e = __expf(S[mt][r] + cs[h * 64 + ii] + pcf[rel * NHEAD + h]);
                } else {
                    e = 0.0f;
                }
                sv[mt][r] = e;
                ssum += e;
            }
        ssum += __shfl_xor(ssum, 16);
        ssum += __shfl_xor(ssum, 32);
        const float inv = 1.0f / ssum;
        if (j < NTOK) {
            #pragma unroll
            for (int mt = 0; mt < 4; ++mt) {
                u32x2 pkv;
                pkv.x = pk2(sv[mt][0] * inv, sv[mt][1] * inv);
                pkv.y = pk2(sv[mt][2] * inv, sv[mt][3] * inv);
                *(u32x2*)(pl + j * PSTR + mt * 16 + quad * 4) = pkv;
            }
        }

        // ---- prefetch next head's WB: live range covers only stage C ----
        {
            const int hn = (h + 1) & 7;
            #pragma unroll
            for (int ntl = 0; ntl < 2; ++ntl)
                #pragma unroll
                for (int kt = 0; kt < 4; ++kt)
                    WBn[ntl][kt] = *(const bf16x8*)(Wcw + hn * 16384 + ((2 * w + ntl) * 16 + lid) * 128 + kt * 32 + quad * 8);
        }

        // P rows are wave-private: same-wave LDS RAW needs only an lgkmcnt drain.
        // (threadfence_block would also drain vmcnt and stall the WB/GA prefetch.)
        asm volatile("s_waitcnt lgkmcnt(0)" ::: "memory");

        // ======== stage C: outacc += P^T x U ========
        __builtin_amdgcn_s_setprio(1);
        #pragma unroll
        for (int kt = 0; kt < 2; ++kt) {
            union { bf16x8 v; u32 u[4]; } Af;
            #pragma unroll
            for (int q2 = 0; q2 < 4; ++q2)
                Af.u[q2] = *(const u32*)(pl + jc * PSTR + kt * 32 + quad * 8 + 2 * q2);
            #pragma unroll
            for (int nt = 0; nt < 8; ++nt) {
                const int dd = nt * 16 + lid;
                bf16x8 Bu = *(const bf16x8*)(usb + dd * 64 + ((((kt * 4 + quad) ^ (dd & 7)) & 7) << 3));
                outacc[nt] = __builtin_amdgcn_mfma_f32_16x16x32_bf16(Af.v, Bu, outacc[nt], 0, 0, 0);
            }
        }
        __builtin_amdgcn_s_setprio(0);
        // no end-of-head barrier: next head writes the OTHER ts/us buffer
    }

    // ======== epilogue: out[n][dd][p(j)] = acc + bo[dd]  (fp32 output) ========
    float* outp = out + n * DDIM * PTOT;
    #pragma unroll
    for (int nt = 0; nt < 8; ++nt) {
        const int dd = nt * 16 + lid;
        const float bov = bo[dd];
        #pragma unroll
        for (int r = 0; r < 4; ++r) {
            const int jj = 16 * w + quad * 4 + r;
            if (jj < NTOK) {
                const int a = jj / 7, b = jj - a * 7;
                outp[dd * PTOT + pbase + a * CWID + b] = outacc[nt][r] + bov;
            }
        }
    }
}

extern "C" void kernel_launch(void* const* d_in, const int* in_sizes, int n_in,
                              void* d_out, int out_size, void* d_ws, size_t ws_size,
                              hipStream_t stream) {
    (void)in_sizes; (void)n_in; (void)ws_size; (void)out_size;
    prep<<<128, 256, 0, stream>>>((const float*)d_in[1], (const float*)d_in[3],
                                  (const float*)d_in[5], (const float*)d_in[7],
                                  (const float*)d_in[2], (const float*)d_in[4],
                                  (const float*)d_in[6], (u16*)d_ws);
    winattn<<<NBATCH * 256, 256, 0, stream>>>(
        (const float*)d_in[0], (const u16*)d_ws,
        (const float*)d_in[8], (const float*)d_in[9], (float*)d_out);
}